// Round 8
// baseline (441.515 us; speedup 1.0000x reference)
//
#include <hip/hip_runtime.h>
#include <hip/hip_bf16.h>
#include <stdint.h>
#include <stddef.h>

typedef __bf16 bf16;
typedef bf16 bf16x8 __attribute__((ext_vector_type(8)));
typedef float f32x4 __attribute__((ext_vector_type(4)));

#define N_ROWS 65536
#define EMB    1024
#define ATTD   512
#define KDIM   2048
#define BM     128
#define BN     128
#define BK     64
#define NKB    (KDIM / BK)     // 32 K-tiles
#define MBLK   (N_ROWS / BM)   // 512 row-blocks
#define NSPL   (ATTD / BN)     // 4 col-blocks

__device__ __forceinline__ void gload_lds16(const void* g, void* l) {
  __builtin_amdgcn_global_load_lds(
      (const __attribute__((address_space(1))) void*)g,
      (__attribute__((address_space(3))) void*)l, 16, 0, 0);
}

// ---------------------------------------------------------------------------
// K0: W1 [2048x512] f32 -> W1t bf16: 32x4 per-(kb,bn) 16 KiB images.
// Image (kb,bn), elem (n*8+p)*8+e  holds  W1[kb*64 + (p^(n&7))*8 + e][bn*128+n].
// ---------------------------------------------------------------------------
__global__ __launch_bounds__(256) void k_prep_w1(const float* __restrict__ W1,
                                                 bf16* __restrict__ W1t) {
  __shared__ float tile[64][132];
  const int kb = blockIdx.x;   // 0..31
  const int bn = blockIdx.y;   // 0..3
  const int t  = threadIdx.x;  // 0..255

  const int kr = t >> 2;             // 0..63
  const int nc = (t & 3) * 32;       // 0,32,64,96
  const float* src = W1 + (size_t)(kb * 64 + kr) * ATTD + bn * 128 + nc;
  #pragma unroll
  for (int q = 0; q < 8; ++q) {
    float4 v = *(const float4*)(src + q * 4);
    tile[kr][nc + q * 4 + 0] = v.x;
    tile[kr][nc + q * 4 + 1] = v.y;
    tile[kr][nc + q * 4 + 2] = v.z;
    tile[kr][nc + q * 4 + 3] = v.w;
  }
  __syncthreads();

  const int nl = t >> 1;             // 0..127
  const int pb = (t & 1) * 4;
  bf16* dst = W1t + (size_t)(kb * 4 + bn) * (BN * BK);
  #pragma unroll
  for (int pi = 0; pi < 4; ++pi) {
    const int p = pb + pi;
    const int c = p ^ (nl & 7);
    bf16x8 o;
    #pragma unroll
    for (int e = 0; e < 8; ++e) o[e] = (bf16)tile[c * 8 + e][nl];
    *(bf16x8*)(dst + ((size_t)nl * 8 + p) * 8) = o;
  }
}

// ---------------------------------------------------------------------------
// K1: 128x128-tile fused GEMM -> partial scores.  2048 blocks, 256 thr
// (4 waves 2x2), BK=64.  Structure (R8):
//  * XCD-affinity remap (R5-proven: FETCH 1.08GB -> 0.34GB).
//  * A: f32 prefetched to REGS at top of compute phase (issued right after a
//    barrier, drained by the post-compute barrier -> latency hidden under 32
//    MFMAs); cvt+swizzled ds_write is the only serial stage work (~100cy).
//  * B: DMA to double-buffered LDS, issued with the A prefetch (fires into
//    ldsB[nxt] while compute reads ldsB[cur]).  A single-buffered.
//  * 48 KiB LDS -> 3 blocks/CU; no asm waits, no sched_barriers (R2/R3/R6
//    lessons: issue placement only, let the compiler schedule).
// spart[bn][m] = sum_{col in bn-slice} tanh(h[m][col]+b1[col]) * W2[col]
// ---------------------------------------------------------------------------
__global__ __launch_bounds__(256, 3) void k_gemm_score(
    const float* __restrict__ leaves, const float* __restrict__ anc,
    const bf16* __restrict__ W1t, const float* __restrict__ b1,
    const float* __restrict__ W2, float* __restrict__ spart) {
  __shared__ bf16 ldsA[BM * BK];     // 16 KiB (single)
  __shared__ bf16 ldsB[2][BN * BK];  // 2 x 16 KiB (dbuf)

  const int t    = threadIdx.x;
  const int lane = t & 63;
  const int wave = t >> 6;
  const int l15  = lane & 15;
  const int l4   = lane >> 4;
  const int wm2  = wave >> 1;  // 0..1
  const int wn2  = wave & 1;   // 0..1

  // --- XCD-affinity remap: the 4 bn-sharers of one row-slab sit 8 apart in
  //     dispatch id -> same XCD -> per-kb A-tile L2 reuse. ---
  const int g   = blockIdx.x;
  const int sb  = g >> 5;        // superblock 0..63
  const int q   = g & 31;
  const int bn  = q >> 3;        // 0..3
  const int bm  = sb * 8 + (q & 7);
  const int m0  = bm * BM;
  const int n0  = bn * BN;

  // A staging: 2 threads/row, 32 f32 (4 chunks of 8) each
  const int ar = t >> 1;       // 0..127
  const int c0 = (t & 1) * 4;  // logical chunk base
  int a_wr[4];
  #pragma unroll
  for (int i = 0; i < 4; ++i)
    a_wr[i] = ar * BK + ((c0 + i) ^ (ar & 7)) * 8;

  // fragment read offsets
  int a_rd[2][4], b_rd[2][4];
  #pragma unroll
  for (int ks = 0; ks < 2; ++ks) {
    #pragma unroll
    for (int mi = 0; mi < 4; ++mi) {
      const int row = wm2 * 64 + mi * 16 + l15;
      a_rd[ks][mi] = row * BK + ((ks * 4 + l4) ^ (row & 7)) * 8;
    }
    #pragma unroll
    for (int ni = 0; ni < 4; ++ni) {
      const int nrow = wn2 * 64 + ni * 16 + l15;
      b_rd[ks][ni] = nrow * BK + ((ks * 4 + l4) ^ (nrow & 7)) * 8;
    }
  }

  const f32x4 zero4 = {0.f, 0.f, 0.f, 0.f};
  f32x4 acc[4][4];
  #pragma unroll
  for (int i = 0; i < 4; ++i)
    #pragma unroll
    for (int j = 0; j < 4; ++j) acc[i][j] = zero4;

  float4 rA[8];

  auto issueB = [&](int kb, int buf) {
    const bf16* Bsrc = W1t + (size_t)(kb * 4 + bn) * (BN * BK);
    #pragma unroll
    for (int j = 0; j < 4; ++j)
      gload_lds16(Bsrc + ((size_t)(wave * 4 + j) * 64 + lane) * 8,
                  &ldsB[buf][(wave * 4 + j) * 512]);
  };
  auto loadA = [&](int kb) {
    const float* Ap = ((kb < 16)
        ? leaves + (size_t)(m0 + ar) * EMB + (size_t)kb * BK
        : anc    + (size_t)(m0 + ar) * EMB + (size_t)(kb - 16) * BK)
        + c0 * 8;
    #pragma unroll
    for (int qi = 0; qi < 8; ++qi)
      rA[qi] = *(const float4*)(Ap + qi * 4);
  };
  auto writeA = [&]() {
    #pragma unroll
    for (int i = 0; i < 4; ++i) {
      const float4 va = rA[2 * i], vb = rA[2 * i + 1];
      bf16x8 o = {(bf16)va.x, (bf16)va.y, (bf16)va.z, (bf16)va.w,
                  (bf16)vb.x, (bf16)vb.y, (bf16)vb.z, (bf16)vb.w};
      *(bf16x8*)(&ldsA[a_wr[i]]) = o;
    }
  };

  // ---- prologue: tile 0 staged (one exposed A-latency, once) ----
  loadA(0);
  issueB(0, 0);
  writeA();          // waits on rA loads
  __syncthreads();   // drains B(0) DMA

  for (int kb = 0; kb < NKB; ++kb) {
    const int cur = kb & 1, nxt = cur ^ 1;
    const bool pf = (kb + 1 < NKB);
    // issue next-tile prefetches right after the barrier; the post-compute
    // barrier's implicit vmcnt(0) drain is then hidden under the MFMAs.
    if (pf) {
      loadA(kb + 1);          // HBM -> regs (fire)
      issueB(kb + 1, nxt);    // L2  -> ldsB[nxt] DMA (fire)
    }
    // ---- compute tile kb ----
    #pragma unroll
    for (int ks = 0; ks < 2; ++ks) {
      bf16x8 af[4], bfr[4];
      #pragma unroll
      for (int mi = 0; mi < 4; ++mi)
        af[mi] = *(const bf16x8*)(&ldsA[a_rd[ks][mi]]);
      #pragma unroll
      for (int ni = 0; ni < 4; ++ni)
        bfr[ni] = *(const bf16x8*)(&ldsB[cur][b_rd[ks][ni]]);
      #pragma unroll
      for (int ni = 0; ni < 4; ++ni)
        #pragma unroll
        for (int mi = 0; mi < 4; ++mi)
          acc[mi][ni] = __builtin_amdgcn_mfma_f32_16x16x32_bf16(
              af[mi], bfr[ni], acc[mi][ni], 0, 0, 0);
    }
    __syncthreads();   // drains A(kb+1)/B(kb+1) — hidden by compute above
    if (pf) writeA();  // cvt + swizzled ds_write into ldsA (short)
    __syncthreads();   // ldsA visible for next compute
  }

  // ---- epilogue: partial score over this block's 128 cols ----
  // acc[mi][ni][r]: row = wm2*64+mi*16+l4*4+r, col = wn2*64+ni*16+l15
  float b1c[4], w2c[4];
  #pragma unroll
  for (int ni = 0; ni < 4; ++ni) {
    const int col = n0 + wn2 * 64 + ni * 16 + l15;
    b1c[ni] = b1[col];
    w2c[ni] = W2[col];
  }
  float* sp = (float*)ldsA;  // 256 floats scratch
  #pragma unroll
  for (int mi = 0; mi < 4; ++mi) {
    #pragma unroll
    for (int r = 0; r < 4; ++r) {
      float p = 0.f;
      #pragma unroll
      for (int ni = 0; ni < 4; ++ni)
        p += tanhf(acc[mi][ni][r] + b1c[ni]) * w2c[ni];
      p += __shfl_xor(p, 1);
      p += __shfl_xor(p, 2);
      p += __shfl_xor(p, 4);
      p += __shfl_xor(p, 8);
      if (l15 == 0) sp[wn2 * 128 + wm2 * 64 + mi * 16 + l4 * 4 + r] = p;
    }
  }
  __syncthreads();
  if (t < BM)
    spart[(size_t)bn * N_ROWS + m0 + t] = sp[t] + sp[128 + t];
}

// ---------------------------------------------------------------------------
// K2: combine 4 partials -> scores; per-128-row block max & sumexp.
// ---------------------------------------------------------------------------
__global__ __launch_bounds__(128) void k_combine(
    const float* __restrict__ spart, const float* __restrict__ b2,
    float* __restrict__ scores, float* __restrict__ bmax,
    float* __restrict__ bsum) {
  const int b = blockIdx.x, t = threadIdx.x;
  const int lane = t & 63, wave = t >> 6;
  const int m = b * 128 + t;
  __shared__ float rm[2], rs[2];
  const float s = spart[m] + spart[N_ROWS + m] + spart[2 * N_ROWS + m] +
                  spart[3 * N_ROWS + m] + b2[0];
  scores[m] = s;
  float mm = s;
  #pragma unroll
  for (int o = 32; o; o >>= 1) mm = fmaxf(mm, __shfl_xor(mm, o));
  if (lane == 0) rm[wave] = mm;
  __syncthreads();
  const float bM = fmaxf(rm[0], rm[1]);
  float ee = __expf(s - bM);
  #pragma unroll
  for (int o = 32; o; o >>= 1) ee += __shfl_xor(ee, o);
  if (lane == 0) rs[wave] = ee;
  __syncthreads();
  if (t == 0) {
    bmax[b] = bM;
    bsum[b] = rs[0] + rs[1];
  }
}

// ---------------------------------------------------------------------------
// K3: global M, Z and per-block rescale factors scale[b] = exp(bmax[b]-M).
// ---------------------------------------------------------------------------
__global__ __launch_bounds__(512) void k_mz(const float* __restrict__ bmax,
                                            const float* __restrict__ bsum,
                                            float* __restrict__ MZ,
                                            float* __restrict__ scale) {
  const int t = threadIdx.x, lane = t & 63, wave = t >> 6;
  __shared__ float rm[8], rs[8];
  const float m = bmax[t];
  float mm = m;
  #pragma unroll
  for (int o = 32; o; o >>= 1) mm = fmaxf(mm, __shfl_xor(mm, o));
  if (lane == 0) rm[wave] = mm;
  __syncthreads();
  if (t == 0) {
    float g = rm[0];
    for (int i = 1; i < 8; ++i) g = fmaxf(g, rm[i]);
    rm[0] = g;
  }
  __syncthreads();
  const float M = rm[0];
  const float sc = __expf(m - M);
  scale[t] = sc;
  float z = bsum[t] * sc;
  #pragma unroll
  for (int o = 32; o; o >>= 1) z += __shfl_xor(z, o);
  if (lane == 0) rs[wave] = z;
  __syncthreads();
  if (t == 0) {
    float Z = 0.f;
    for (int i = 0; i < 8; ++i) Z += rs[i];
    MZ[0] = M;
    MZ[1] = Z;
  }
}

// ---------------------------------------------------------------------------
// K4: part[b][j] = sum_i exp(s_i - bmax[b]) * anc[b*128+i][j]   (local max)
// ---------------------------------------------------------------------------
__global__ __launch_bounds__(256) void k_part(const float* __restrict__ anc,
                                              const float* __restrict__ scores,
                                              const float* __restrict__ bmax,
                                              float* __restrict__ part) {
  __shared__ float w[BM];
  const int b = blockIdx.x, t = threadIdx.x;
  const float bM = bmax[b];
  if (t < BM) w[t] = __expf(scores[(size_t)b * BM + t] - bM);
  __syncthreads();
  float4 a = {0.f, 0.f, 0.f, 0.f};
  const float4* src = (const float4*)(anc + (size_t)b * BM * EMB) + t;
  #pragma unroll 4
  for (int i = 0; i < BM; ++i) {
    float4 v = src[i * (EMB / 4)];
    const float wi = w[i];
    a.x += wi * v.x;
    a.y += wi * v.y;
    a.z += wi * v.z;
    a.w += wi * v.w;
  }
  ((float4*)(part + (size_t)b * EMB))[t] = a;
}

// ---------------------------------------------------------------------------
// K5: out[j] = (sum_b part[b][j] * scale[b]) / Z
// ---------------------------------------------------------------------------
__global__ __launch_bounds__(256) void k_final(const float* __restrict__ part,
                                               const float* __restrict__ scale,
                                               const float* __restrict__ MZ,
                                               float* __restrict__ out) {
  const int j = blockIdx.x * 256 + threadIdx.x;
  float s0 = 0.f, s1 = 0.f, s2 = 0.f, s3 = 0.f;
  for (int b = 0; b < MBLK; b += 4) {
    s0 += part[(size_t)(b + 0) * EMB + j] * scale[b + 0];
    s1 += part[(size_t)(b + 1) * EMB + j] * scale[b + 1];
    s2 += part[(size_t)(b + 2) * EMB + j] * scale[b + 2];
    s3 += part[(size_t)(b + 3) * EMB + j] * scale[b + 3];
  }
  out[j] = (s0 + s1 + s2 + s3) / MZ[1];
}

extern "C" void kernel_launch(void* const* d_in, const int* in_sizes, int n_in,
                              void* d_out, int out_size, void* d_ws,
                              size_t ws_size, hipStream_t stream) {
  const float* leaves = (const float*)d_in[0];
  const float* anc    = (const float*)d_in[1];
  const float* W1     = (const float*)d_in[2];
  const float* b1     = (const float*)d_in[3];
  const float* W2     = (const float*)d_in[4];
  const float* b2     = (const float*)d_in[5];
  float* out = (float*)d_out;

  char* ws = (char*)d_ws;
  bf16*  W1t    = (bf16*)ws;                                   // 2 MiB
  float* spart  = (float*)(ws + (2u << 20));                   // 1 MiB
  float* scores = (float*)(ws + (3u << 20));                   // 256 KiB
  float* bmax   = (float*)(ws + (3u << 20) + (1u << 18));      // 2 KiB
  float* bsum   = bmax + MBLK;                                 // 2 KiB
  float* scale  = bsum + MBLK;                                 // 2 KiB
  float* MZ     = scale + MBLK;                                // 8 B
  float* part   = (float*)(ws + (4u << 20));                   // 2 MiB

  k_prep_w1<<<dim3(32, 4), 256, 0, stream>>>(W1, W1t);
  k_gemm_score<<<dim3(MBLK * NSPL), 256, 0, stream>>>(leaves, anc, W1t, b1, W2,
                                                      spart);
  k_combine<<<dim3(MBLK), 128, 0, stream>>>(spart, b2, scores, bmax, bsum);
  k_mz<<<dim3(1), 512, 0, stream>>>(bmax, bsum, MZ, scale);
  k_part<<<dim3(MBLK), 256, 0, stream>>>(anc, scores, bmax, part);
  k_final<<<dim3(EMB / 256), 256, 0, stream>>>(part, scale, MZ, out);
}

// Round 9
// 291.784 us; speedup vs baseline: 1.5132x; 1.5132x over previous
//
#include <hip/hip_runtime.h>
#include <hip/hip_bf16.h>
#include <stdint.h>
#include <stddef.h>

typedef __bf16 bf16;
typedef bf16 bf16x8 __attribute__((ext_vector_type(8)));
typedef float f32x4 __attribute__((ext_vector_type(4)));

#define N_ROWS 65536
#define EMB    1024
#define ATTD   512
#define KDIM   2048
#define BM     128
#define BN     128
#define BK     64
#define NKB    (KDIM / BK)     // 32 K-tiles
#define MBLK   (N_ROWS / BM)   // 512 row-blocks
#define NSPL   (ATTD / BN)     // 4 col-blocks

__device__ __forceinline__ void gload_lds16(const void* g, void* l) {
  __builtin_amdgcn_global_load_lds(
      (const __attribute__((address_space(1))) void*)g,
      (__attribute__((address_space(3))) void*)l, 16, 0, 0);
}

// ---------------------------------------------------------------------------
// K0: W1 [2048x512] f32 -> W1t bf16: 32x4 per-(kb,bn) 16 KiB images.
// Image (kb,bn), elem (n*8+p)*8+e  holds  W1[kb*64 + (p^(n&7))*8 + e][bn*128+n].
// ---------------------------------------------------------------------------
__global__ __launch_bounds__(256) void k_prep_w1(const float* __restrict__ W1,
                                                 bf16* __restrict__ W1t) {
  __shared__ float tile[64][132];
  const int kb = blockIdx.x;   // 0..31
  const int bn = blockIdx.y;   // 0..3
  const int t  = threadIdx.x;  // 0..255

  const int kr = t >> 2;             // 0..63
  const int nc = (t & 3) * 32;       // 0,32,64,96
  const float* src = W1 + (size_t)(kb * 64 + kr) * ATTD + bn * 128 + nc;
  #pragma unroll
  for (int q = 0; q < 8; ++q) {
    float4 v = *(const float4*)(src + q * 4);
    tile[kr][nc + q * 4 + 0] = v.x;
    tile[kr][nc + q * 4 + 1] = v.y;
    tile[kr][nc + q * 4 + 2] = v.z;
    tile[kr][nc + q * 4 + 3] = v.w;
  }
  __syncthreads();

  const int nl = t >> 1;             // 0..127
  const int pb = (t & 1) * 4;
  bf16* dst = W1t + (size_t)(kb * 4 + bn) * (BN * BK);
  #pragma unroll
  for (int pi = 0; pi < 4; ++pi) {
    const int p = pb + pi;
    const int c = p ^ (nl & 7);
    bf16x8 o;
    #pragma unroll
    for (int e = 0; e < 8; ++e) o[e] = (bf16)tile[c * 8 + e][nl];
    *(bf16x8*)(dst + ((size_t)nl * 8 + p) * 8) = o;
  }
}

// ---------------------------------------------------------------------------
// K1: 128x128-tile fused GEMM -> partial scores.  2048 blocks, 256 thr
// (4 waves 2x2), BK=64, single-buffered LDS, 2-barrier loop (R5 structure —
// fastest measured; all reg-staged / pipelined variants regressed).
//  * XCD-affinity remap (R5-proven: FETCH 1.08GB -> 0.34GB).
//  * A staged via f32 global_load_lds DMA with pre-swizzled SOURCE address,
//    linear LDS dest (rule #21).  R9 change vs R5: swizzle granularity
//    32B -> 16B (phys_unit = u ^ (row&7), full 3-bit XOR within the 128B
//    bank wrap) -> 2-way aliasing only (free), was 4-way (1.58x).
//  * B via global_load_lds from pre-swizzled bf16 images (0 conflicts, R4).
// spart[bn][m] = sum_{col in bn-slice} tanh(h[m][col]+b1[col]) * W2[col]
// ---------------------------------------------------------------------------
__global__ __launch_bounds__(256, 3) void k_gemm_score(
    const float* __restrict__ leaves, const float* __restrict__ anc,
    const bf16* __restrict__ W1t, const float* __restrict__ b1,
    const float* __restrict__ W2, float* __restrict__ spart) {
  __shared__ float ldsAf[BM * BK];  // 32 KiB f32, 16B-unit XOR-swizzled
  __shared__ bf16  ldsB[BN * BK];   // 16 KiB bf16, chunk-swizzled

  const int t    = threadIdx.x;
  const int lane = t & 63;
  const int wave = t >> 6;
  const int l15  = lane & 15;
  const int l4   = lane >> 4;
  const int wm2  = wave >> 1;  // 0..1
  const int wn2  = wave & 1;   // 0..1

  // --- XCD-affinity remap: the 4 bn-sharers of one row-slab sit 8 apart in
  //     dispatch id -> same XCD -> per-kb A-tile L2 reuse. ---
  const int g   = blockIdx.x;
  const int sb  = g >> 5;        // superblock 0..63
  const int q   = g & 31;
  const int bn  = q >> 3;        // 0..3
  const int bm  = sb * 8 + (q & 7);
  const int m0  = bm * BM;
  const int n0  = bn * BN;

  // --- A DMA source pre-swizzle (per-thread constants) ---
  // Issue s, thread t -> LDS 16B unit (s*256+t): row r = s*16 + (t>>4),
  // phys unit p = t&15.  Logical unit u = p ^ (r&7); r&7 == (t>>4)&7.
  // Stored: ldsAf[r*64 + p*4 .. +3] = A[r][kb*64 + u*4 .. +3].
  const int a_rbase = t >> 4;                         // row for s=0; +16 per s
  const int a_koff  = ((t & 15) ^ ((t >> 4) & 7)) * 4;  // f32 offset in k-win

  const f32x4 zero4 = {0.f, 0.f, 0.f, 0.f};
  f32x4 acc[4][4];
  #pragma unroll
  for (int i = 0; i < 4; ++i)
    #pragma unroll
    for (int j = 0; j < 4; ++j) acc[i][j] = zero4;

  // A fragment read offsets: fragment (row, c) needs f32 k=8c..8c+7 =
  // logical units 2c, 2c+1 at phys (2c)^(r&7), (2c+1)^(r&7) (may be swapped
  // in place for odd rows -> address each 16B half explicitly).
  int a_rd_lo[2][4], a_rd_hi[2][4], b_rd[2][4];
  #pragma unroll
  for (int ks = 0; ks < 2; ++ks) {
    #pragma unroll
    for (int mi = 0; mi < 4; ++mi) {
      const int row = wm2 * 64 + mi * 16 + l15;
      const int c   = ks * 4 + l4;
      const int s3  = row & 7;
      a_rd_lo[ks][mi] = row * BK + ((2 * c)     ^ s3) * 4;
      a_rd_hi[ks][mi] = row * BK + ((2 * c + 1) ^ s3) * 4;
    }
    #pragma unroll
    for (int ni = 0; ni < 4; ++ni) {
      const int nrow = wn2 * 64 + ni * 16 + l15;
      b_rd[ks][ni] = nrow * BK + ((ks * 4 + l4) ^ (nrow & 7)) * 8;
    }
  }

  for (int kb = 0; kb < NKB; ++kb) {
    // ---- B: 16 KiB pre-swizzled image -> LDS (linear dest) ----
    const bf16* Bsrc = W1t + (size_t)(kb * 4 + bn) * (BN * BK);
    #pragma unroll
    for (int j = 0; j < 4; ++j)
      gload_lds16(Bsrc + ((size_t)(wave * 4 + j) * 64 + lane) * 8,
                  ldsB + (wave * 4 + j) * 512);
    // ---- A: f32 DMA, pre-swizzled source, linear dest ----
    const float* Abase = (kb < 16)
        ? leaves + (size_t)m0 * EMB + (size_t)kb * BK
        : anc    + (size_t)m0 * EMB + (size_t)(kb - 16) * BK;
    #pragma unroll
    for (int s = 0; s < 8; ++s) {
      const int r = s * 16 + a_rbase;
      gload_lds16(Abase + (size_t)r * EMB + a_koff,
                  ldsAf + (s * 256 + t) * 4);
    }
    __syncthreads();
    // ---- compute ----
    #pragma unroll
    for (int ks = 0; ks < 2; ++ks) {
      bf16x8 af[4], bfr[4];
      #pragma unroll
      for (int mi = 0; mi < 4; ++mi) {
        f32x4 lo = *(const f32x4*)(ldsAf + a_rd_lo[ks][mi]);
        f32x4 hi = *(const f32x4*)(ldsAf + a_rd_hi[ks][mi]);
        af[mi] = (bf16x8){(bf16)lo.x, (bf16)lo.y, (bf16)lo.z, (bf16)lo.w,
                          (bf16)hi.x, (bf16)hi.y, (bf16)hi.z, (bf16)hi.w};
      }
      #pragma unroll
      for (int ni = 0; ni < 4; ++ni)
        bfr[ni] = *(const bf16x8*)(ldsB + b_rd[ks][ni]);
      #pragma unroll
      for (int ni = 0; ni < 4; ++ni)
        #pragma unroll
        for (int mi = 0; mi < 4; ++mi)
          acc[mi][ni] = __builtin_amdgcn_mfma_f32_16x16x32_bf16(
              af[mi], bfr[ni], acc[mi][ni], 0, 0, 0);
    }
    __syncthreads();
  }

  // ---- epilogue: partial score over this block's 128 cols ----
  // acc[mi][ni][r]: row = wm2*64+mi*16+l4*4+r, col = wn2*64+ni*16+l15
  float b1c[4], w2c[4];
  #pragma unroll
  for (int ni = 0; ni < 4; ++ni) {
    const int col = n0 + wn2 * 64 + ni * 16 + l15;
    b1c[ni] = b1[col];
    w2c[ni] = W2[col];
  }
  float* sp = ldsAf;  // 256 floats scratch
  #pragma unroll
  for (int mi = 0; mi < 4; ++mi) {
    #pragma unroll
    for (int r = 0; r < 4; ++r) {
      float p = 0.f;
      #pragma unroll
      for (int ni = 0; ni < 4; ++ni)
        p += tanhf(acc[mi][ni][r] + b1c[ni]) * w2c[ni];
      p += __shfl_xor(p, 1);
      p += __shfl_xor(p, 2);
      p += __shfl_xor(p, 4);
      p += __shfl_xor(p, 8);
      if (l15 == 0) sp[wn2 * 128 + wm2 * 64 + mi * 16 + l4 * 4 + r] = p;
    }
  }
  __syncthreads();
  if (t < BM)
    spart[(size_t)bn * N_ROWS + m0 + t] = sp[t] + sp[128 + t];
}

// ---------------------------------------------------------------------------
// K2: combine 4 partials -> scores; per-128-row block max & sumexp.
// ---------------------------------------------------------------------------
__global__ __launch_bounds__(128) void k_combine(
    const float* __restrict__ spart, const float* __restrict__ b2,
    float* __restrict__ scores, float* __restrict__ bmax,
    float* __restrict__ bsum) {
  const int b = blockIdx.x, t = threadIdx.x;
  const int lane = t & 63, wave = t >> 6;
  const int m = b * 128 + t;
  __shared__ float rm[2], rs[2];
  const float s = spart[m] + spart[N_ROWS + m] + spart[2 * N_ROWS + m] +
                  spart[3 * N_ROWS + m] + b2[0];
  scores[m] = s;
  float mm = s;
  #pragma unroll
  for (int o = 32; o; o >>= 1) mm = fmaxf(mm, __shfl_xor(mm, o));
  if (lane == 0) rm[wave] = mm;
  __syncthreads();
  const float bM = fmaxf(rm[0], rm[1]);
  float ee = __expf(s - bM);
  #pragma unroll
  for (int o = 32; o; o >>= 1) ee += __shfl_xor(ee, o);
  if (lane == 0) rs[wave] = ee;
  __syncthreads();
  if (t == 0) {
    bmax[b] = bM;
    bsum[b] = rs[0] + rs[1];
  }
}

// ---------------------------------------------------------------------------
// K3: global M, Z and per-block rescale factors scale[b] = exp(bmax[b]-M).
// ---------------------------------------------------------------------------
__global__ __launch_bounds__(512) void k_mz(const float* __restrict__ bmax,
                                            const float* __restrict__ bsum,
                                            float* __restrict__ MZ,
                                            float* __restrict__ scale) {
  const int t = threadIdx.x, lane = t & 63, wave = t >> 6;
  __shared__ float rm[8], rs[8];
  const float m = bmax[t];
  float mm = m;
  #pragma unroll
  for (int o = 32; o; o >>= 1) mm = fmaxf(mm, __shfl_xor(mm, o));
  if (lane == 0) rm[wave] = mm;
  __syncthreads();
  if (t == 0) {
    float g = rm[0];
    for (int i = 1; i < 8; ++i) g = fmaxf(g, rm[i]);
    rm[0] = g;
  }
  __syncthreads();
  const float M = rm[0];
  const float sc = __expf(m - M);
  scale[t] = sc;
  float z = bsum[t] * sc;
  #pragma unroll
  for (int o = 32; o; o >>= 1) z += __shfl_xor(z, o);
  if (lane == 0) rs[wave] = z;
  __syncthreads();
  if (t == 0) {
    float Z = 0.f;
    for (int i = 0; i < 8; ++i) Z += rs[i];
    MZ[0] = M;
    MZ[1] = Z;
  }
}

// ---------------------------------------------------------------------------
// K4: part[b][j] = sum_i exp(s_i - bmax[b]) * anc[b*128+i][j]   (local max)
// ---------------------------------------------------------------------------
__global__ __launch_bounds__(256) void k_part(const float* __restrict__ anc,
                                              const float* __restrict__ scores,
                                              const float* __restrict__ bmax,
                                              float* __restrict__ part) {
  __shared__ float w[BM];
  const int b = blockIdx.x, t = threadIdx.x;
  const float bM = bmax[b];
  if (t < BM) w[t] = __expf(scores[(size_t)b * BM + t] - bM);
  __syncthreads();
  float4 a = {0.f, 0.f, 0.f, 0.f};
  const float4* src = (const float4*)(anc + (size_t)b * BM * EMB) + t;
  #pragma unroll 4
  for (int i = 0; i < BM; ++i) {
    float4 v = src[i * (EMB / 4)];
    const float wi = w[i];
    a.x += wi * v.x;
    a.y += wi * v.y;
    a.z += wi * v.z;
    a.w += wi * v.w;
  }
  ((float4*)(part + (size_t)b * EMB))[t] = a;
}

// ---------------------------------------------------------------------------
// K5: out[j] = (sum_b part[b][j] * scale[b]) / Z
// ---------------------------------------------------------------------------
__global__ __launch_bounds__(256) void k_final(const float* __restrict__ part,
                                               const float* __restrict__ scale,
                                               const float* __restrict__ MZ,
                                               float* __restrict__ out) {
  const int j = blockIdx.x * 256 + threadIdx.x;
  float s0 = 0.f, s1 = 0.f, s2 = 0.f, s3 = 0.f;
  for (int b = 0; b < MBLK; b += 4) {
    s0 += part[(size_t)(b + 0) * EMB + j] * scale[b + 0];
    s1 += part[(size_t)(b + 1) * EMB + j] * scale[b + 1];
    s2 += part[(size_t)(b + 2) * EMB + j] * scale[b + 2];
    s3 += part[(size_t)(b + 3) * EMB + j] * scale[b + 3];
  }
  out[j] = (s0 + s1 + s2 + s3) / MZ[1];
}

extern "C" void kernel_launch(void* const* d_in, const int* in_sizes, int n_in,
                              void* d_out, int out_size, void* d_ws,
                              size_t ws_size, hipStream_t stream) {
  const float* leaves = (const float*)d_in[0];
  const float* anc    = (const float*)d_in[1];
  const float* W1     = (const float*)d_in[2];
  const float* b1     = (const float*)d_in[3];
  const float* W2     = (const float*)d_in[4];
  const float* b2     = (const float*)d_in[5];
  float* out = (float*)d_out;

  char* ws = (char*)d_ws;
  bf16*  W1t    = (bf16*)ws;                                   // 2 MiB
  float* spart  = (float*)(ws + (2u << 20));                   // 1 MiB
  float* scores = (float*)(ws + (3u << 20));                   // 256 KiB
  float* bmax   = (float*)(ws + (3u << 20) + (1u << 18));      // 2 KiB
  float* bsum   = bmax + MBLK;                                 // 2 KiB
  float* scale  = bsum + MBLK;                                 // 2 KiB
  float* MZ     = scale + MBLK;                                // 8 B
  float* part   = (float*)(ws + (4u << 20));                   // 2 MiB

  k_prep_w1<<<dim3(32, 4), 256, 0, stream>>>(W1, W1t);
  k_gemm_score<<<dim3(MBLK * NSPL), 256, 0, stream>>>(leaves, anc, W1t, b1, W2,
                                                      spart);
  k_combine<<<dim3(MBLK), 128, 0, stream>>>(spart, b2, scores, bmax, bsum);
  k_mz<<<dim3(1), 512, 0, stream>>>(bmax, bsum, MZ, scale);
  k_part<<<dim3(MBLK), 256, 0, stream>>>(anc, scores, bmax, part);
  k_final<<<dim3(EMB / 256), 256, 0, stream>>>(part, scale, MZ, out);
}